// Round 14
// baseline (190.285 us; speedup 1.0000x reference)
//
#include <hip/hip_runtime.h>
#include <math.h>

#define BB 2
#define NN 512
#define DD 128
#define HH 8
#define DKK 16
#define TR 64            // tile rows
#define NT 4             // tiles per block (256 rows)
#define ETS2 520         // attn LDS row stride

typedef __attribute__((ext_vector_type(8))) short short8;
typedef __attribute__((ext_vector_type(4))) float f32x4;

__device__ __forceinline__ float dot4(float4 a, float4 b) {
    return a.x*b.x + a.y*b.y + a.z*b.z + a.w*b.w;
}
// RNE f32 -> bf16 pack (a in low, b in high)
__device__ __forceinline__ unsigned pk_bf16(float a, float b) {
    unsigned ua = __float_as_uint(a), ub = __float_as_uint(b);
    ua = (ua + 0x7FFFu + ((ua >> 16) & 1u)) >> 16;
    ub = (ub + 0x7FFFu + ((ub >> 16) & 1u)) >> 16;
    return ua | (ub << 16);
}

// ---------------- Kernel 1: QKV projection + W_egT staging ----------------
__global__ __launch_bounds__(128)
void qkv_kernel(const float* __restrict__ n_in,
                const float* __restrict__ W_qkv,
                const float* __restrict__ W_g,
                const float* __restrict__ W_e,
                float* __restrict__ Qw, float* __restrict__ Kw,
                float* __restrict__ Vw, float* __restrict__ WegT)
{
    const int bid = blockIdx.x;
    if (bid >= BB * NN) {                    // 16 trailing blocks: WegT[col][d]
        const int col = bid - BB * NN;
        const int t = threadIdx.x;
        WegT[col * DD + t] = (col < 8) ? W_e[t * HH + col]
                                       : W_g[t * HH + (col - 8)];
        return;
    }
    __shared__ float nrow[DD];
    const int bn = bid;
    const int b  = bn >> 9;
    const int nr = bn & 511;
    const int t  = threadIdx.x;
    nrow[t] = n_in[(size_t)bn * DD + t];
    __syncthreads();
    const int h = t >> 4, dk = t & 15;
    const size_t dst = ((size_t)(b * HH + h) * NN + nr) * DKK + dk;
    float accq = 0.f, acck = 0.f, accv = 0.f;
    #pragma unroll 8
    for (int d = 0; d < DD; ++d) {
        const float nv = nrow[d];
        const float* wr = W_qkv + (size_t)d * 3 * DD;
        accq += nv * wr[t];
        acck += nv * wr[t + 128];
        accv += nv * wr[t + 256];
    }
    Qw[dst] = accq;
    Kw[dst] = acck;
    Vw[dst] = accv;
}

// ---------------- Kernel 1b: QKc = clamp(Q K^T * scale), [bn][h][m] ----------------
__global__ __launch_bounds__(256)
void qk_kernel(const float* __restrict__ Qw,
               const float* __restrict__ Kw,
               float* __restrict__ QKc)
{
    __shared__ __align__(16) float4 Kl[NN * 4];   // 32KB  [m][4]
    __shared__ __align__(16) float4 Ql[32 * 4];   // 2KB

    const int bid = blockIdx.x;
    const int qt  = bid & 15;
    const int h   = (bid >> 4) & 7;
    const int b   = bid >> 7;
    const int t   = threadIdx.x;

    const float4* __restrict__ kb =
        (const float4*)Kw + ((size_t)(b * HH + h) * NN) * 4;
    #pragma unroll
    for (int j = 0; j < 8; ++j) Kl[j * 256 + t] = kb[j * 256 + t];
    if (t < 128)
        Ql[t] = ((const float4*)Qw)[((size_t)(b * HH + h) * NN + qt * 32) * 4 + t];
    __syncthreads();

    const int qr = t >> 3;
    const int mq = t & 7;
    const float4 q0 = Ql[qr * 4 + 0];
    const float4 q1 = Ql[qr * 4 + 1];
    const float4 q2 = Ql[qr * 4 + 2];
    const float4 q3 = Ql[qr * 4 + 3];

    float4* __restrict__ out4 =
        (float4*)QKc + (((size_t)(b * NN + qt * 32 + qr) * HH + h) * NN) / 4;

    #pragma unroll 1
    for (int cc = 0; cc < 16; ++cc) {
        float4 r;
        float* rp = (float*)&r;
        #pragma unroll
        for (int i = 0; i < 4; ++i) {
            const int m = mq * 64 + cc * 4 + i;
            float s = dot4(q0, Kl[m*4+0]) + dot4(q1, Kl[m*4+1])
                    + dot4(q2, Kl[m*4+2]) + dot4(q3, Kl[m*4+3]);
            s *= 0.25f;
            rp[i] = fminf(5.f, fmaxf(-5.f, s));
        }
        out4[mq * 16 + cc] = r;
    }
}

// ---------------- Kernel 2: E/G MFMA + QKc add + EH + e_out (streaming) ----
// grid = B*N*2 (bn x 2 m-chunks of 256 rows), 256 threads = 4 waves.
// Double-buffered bf16 e-tiles, 2 barriers/tile, no attention tail.
__global__ __launch_bounds__(256)
void eg_kernel(const float* __restrict__ e,
               const float* __restrict__ WegT,
               const float* __restrict__ O_e,
               const float* __restrict__ QKc,
               float* __restrict__ EH,      // [B*N][m][h] _E
               float* __restrict__ Gpart,   // [B*N*2][H]
               float* __restrict__ e_out)
{
    __shared__ __align__(16) uint4 ebuf4[2][TR * 16];  // 2 x 16KB bf16 tiles
    __shared__ __align__(16) float ET2[TR * 8];        // 2KB [m][h]
    __shared__ float Gred[32];

    const int t    = threadIdx.x;
    const int bid  = blockIdx.x;
    const int bn   = bid >> 1;
    const int mc   = bid & 1;
    const int R0   = mc * 256;
    const int wq   = t >> 6;
    const int lane = t & 63;
    const int c    = lane & 15;      // MFMA col (W col / head)
    const int mq   = lane >> 4;      // C/D row group; A/B k-group
    const int c4o  = t & 31;         // e_out float4 column
    const int mg   = t >> 5;         // e_out row base 0..7

    const float4* __restrict__ e4 =
        (const float4*)e + ((size_t)bn * NN + R0) * 32;
    const float4* __restrict__ WegT4 = (const float4*)WegT;

    // B fragments: W[col=c][k], 4 k-steps (16 VGPR)
    short8 wB[4];
    #pragma unroll
    for (int kb = 0; kb < 4; ++kb) {
        const float4 wa = WegT4[c * 32 + kb * 8 + mq * 2];
        const float4 wb = WegT4[c * 32 + kb * 8 + mq * 2 + 1];
        uint4 u;
        u.x = pk_bf16(wa.x, wa.y); u.y = pk_bf16(wa.z, wa.w);
        u.z = pk_bf16(wb.x, wb.y); u.w = pk_bf16(wb.z, wb.w);
        wB[kb] = *(short8*)&u;
    }
    // O_e column cache (32 VGPR)
    float4 oe[8];
    #pragma unroll
    for (int h = 0; h < 8; ++h)
        oe[h] = ((const float4*)O_e)[h * 32 + c4o];

    // stage regs: 8 float4 (32 VGPR)
    float4 pa0, pb0, pa1, pb1, pa2, pb2, pa3, pb3;

    #define STAGE_LOAD(tile)                                                  \
    {                                                                         \
        const float4* __restrict__ sp = e4 + (size_t)(tile) * 2048 + 2 * t;   \
        pa0 = sp[0];    pb0 = sp[1];                                          \
        pa1 = sp[512];  pb1 = sp[513];                                        \
        pa2 = sp[1024]; pb2 = sp[1025];                                       \
        pa3 = sp[1536]; pb3 = sp[1537];                                       \
    }
    #define STAGE_W1(B_, U, A, Bv)                                            \
    {                                                                         \
        const int u_ = (U), ms = u_ >> 4, ck = u_ & 15;                       \
        uint4 x;                                                              \
        x.x = pk_bf16(A.x, A.y);  x.y = pk_bf16(A.z, A.w);                    \
        x.z = pk_bf16(Bv.x, Bv.y); x.w = pk_bf16(Bv.z, Bv.w);                 \
        ebuf4[B_][ms * 16 + (ck ^ (ms & 15))] = x;                            \
    }
    #define STAGE_WRITE(B_)                                                   \
    {                                                                         \
        STAGE_W1(B_, t,       pa0, pb0); STAGE_W1(B_, t + 256, pa1, pb1);     \
        STAGE_W1(B_, t + 512, pa2, pb2); STAGE_W1(B_, t + 768, pa3, pb3);     \
    }

    float ga0 = 0.f, ga1 = 0.f, ga2 = 0.f, ga3 = 0.f;

    STAGE_LOAD(0);
    STAGE_WRITE(0);
    asm volatile("s_waitcnt lgkmcnt(0)" ::: "memory");
    __builtin_amdgcn_s_barrier();

    #pragma unroll
    for (int tt = 0; tt < NT; ++tt) {
        // QKc for this lane's 4 rows (issued early; L2/HBM latency hides)
        float4 qk4 = {0.f, 0.f, 0.f, 0.f};
        if (c < 8)
            qk4 = *(const float4*)(QKc + ((size_t)bn * HH + c) * NN
                                   + R0 + tt * TR + wq * 16 + mq * 4);
        if (tt + 1 < NT) STAGE_LOAD(tt + 1);

        // ---- MFMA ----
        const int mrow = wq * 16 + c;
        f32x4 acc = {0.f, 0.f, 0.f, 0.f};
        #pragma unroll
        for (int kb = 0; kb < 4; ++kb) {
            const int ck = kb * 4 + mq;
            uint4 av = ebuf4[tt & 1][mrow * 16 + (ck ^ (mrow & 15))];
            acc = __builtin_amdgcn_mfma_f32_16x16x32_bf16(
                      *(short8*)&av, wB[kb], acc, 0, 0, 0);
        }

        // ---- epilogue: _E -> ET2 + EH ; G accumulate ----
        const int mloc = wq * 16 + mq * 4;
        if (c < 8) {
            const float v0 = acc[0] + qk4.x;
            const float v1 = acc[1] + qk4.y;
            const float v2 = acc[2] + qk4.z;
            const float v3 = acc[3] + qk4.w;
            ET2[(mloc + 0) * 8 + c] = v0;
            ET2[(mloc + 1) * 8 + c] = v1;
            ET2[(mloc + 2) * 8 + c] = v2;
            ET2[(mloc + 3) * 8 + c] = v3;
            float* ehp = EH + ((size_t)bn * NN + R0 + tt * TR + mloc) * HH + c;
            ehp[0]  = v0;
            ehp[8]  = v1;
            ehp[16] = v2;
            ehp[24] = v3;
        } else {
            ga0 += 1.f / (1.f + __expf(-acc[0]));
            ga1 += 1.f / (1.f + __expf(-acc[1]));
            ga2 += 1.f / (1.f + __expf(-acc[2]));
            ga3 += 1.f / (1.f + __expf(-acc[3]));
        }

        if (tt + 1 < NT) STAGE_WRITE((tt + 1) & 1);
        asm volatile("s_waitcnt lgkmcnt(0)" ::: "memory");
        __builtin_amdgcn_s_barrier();        // ET2 + next buf ready

        // ---- e_out tile ----
        float4* __restrict__ out4 =
            (float4*)e_out + ((size_t)bn * NN + R0 + tt * TR) * 32;
        #pragma unroll
        for (int k = 0; k < 8; ++k) {
            const int m = mg + 8 * k;
            const float4 elo = *(const float4*)&ET2[m * 8];
            const float4 ehi = *(const float4*)&ET2[m * 8 + 4];
            float4 rr;
            rr.x = elo.x*oe[0].x + elo.y*oe[1].x + elo.z*oe[2].x + elo.w*oe[3].x
                 + ehi.x*oe[4].x + ehi.y*oe[5].x + ehi.z*oe[6].x + ehi.w*oe[7].x;
            rr.y = elo.x*oe[0].y + elo.y*oe[1].y + elo.z*oe[2].y + elo.w*oe[3].y
                 + ehi.x*oe[4].y + ehi.y*oe[5].y + ehi.z*oe[6].y + ehi.w*oe[7].y;
            rr.z = elo.x*oe[0].z + elo.y*oe[1].z + elo.z*oe[2].z + elo.w*oe[3].z
                 + ehi.x*oe[4].z + ehi.y*oe[5].z + ehi.z*oe[6].z + ehi.w*oe[7].z;
            rr.w = elo.x*oe[0].w + elo.y*oe[1].w + elo.z*oe[2].w + elo.w*oe[3].w
                 + ehi.x*oe[4].w + ehi.y*oe[5].w + ehi.z*oe[6].w + ehi.w*oe[7].w;
            out4[m * 32 + c4o] = rr;
        }
        __builtin_amdgcn_s_barrier();        // protect ET2 for next tile
    }

    // ---- G partial reduction -> Gpart[bid][h] ----
    if (c >= 8) {
        float s = ga0 + ga1 + ga2 + ga3;
        s += __shfl_xor(s, 16, 64);
        s += __shfl_xor(s, 32, 64);
        if (mq == 0) Gred[wq * 8 + (c - 8)] = s;
    }
    __syncthreads();
    if (t < 8) {
        Gpart[(size_t)bid * HH + t] =
            Gred[t] + Gred[8 + t] + Gred[16 + t] + Gred[24 + t];
    }
    #undef STAGE_LOAD
    #undef STAGE_W1
    #undef STAGE_WRITE
}

// ---------------- Kernel 3: softmax + AV + n_out ----------------
__global__ __launch_bounds__(256)
void attn_kernel(const float* __restrict__ EH,
                 const float* __restrict__ Gpart,
                 const float* __restrict__ Vw,
                 const float* __restrict__ O_n,
                 float* __restrict__ n_out)
{
    __shared__ float ET[HH * ETS2];   // 16.6KB [h][m], stride 520
    __shared__ float dc[HH];
    __shared__ __align__(16) float vout[DD];

    const int t    = threadIdx.x;
    const int bn   = blockIdx.x;
    const int b    = bn >> 9;
    const int wq   = t >> 6;
    const int lane = t & 63;

    // stage EH [m][h] -> ET [h][m] (coalesced float4 reads, ~2-way LDS writes)
    const float4* __restrict__ eh4 = (const float4*)(EH + (size_t)bn * NN * HH);
    #pragma unroll
    for (int k = 0; k < 4; ++k) {
        const float4 f = eh4[t + 256 * k];
        const int idx = (t + 256 * k) << 2;
        const int m = idx >> 3, h0 = idx & 7;
        ET[(h0 + 0) * ETS2 + m] = f.x;
        ET[(h0 + 1) * ETS2 + m] = f.y;
        ET[(h0 + 2) * ETS2 + m] = f.z;
        ET[(h0 + 3) * ETS2 + m] = f.w;
    }
    if (t < HH)
        dc[t] = log1pf(Gpart[(size_t)bn * 2 * HH + t] +
                       Gpart[(size_t)bn * 2 * HH + HH + t]);
    __syncthreads();

    #pragma unroll 1
    for (int hw = 0; hw < 2; ++hw) {
        const int h = wq * 2 + hw;
        float vals[8];
        float rmax = -1e30f;
        #pragma unroll
        for (int k = 0; k < 8; ++k) {
            vals[k] = ET[h * ETS2 + k * 64 + lane];
            rmax = fmaxf(rmax, vals[k]);
        }
        #pragma unroll
        for (int off = 32; off >= 1; off >>= 1)
            rmax = fmaxf(rmax, __shfl_xor(rmax, off, 64));
        float sum = 0.f;
        #pragma unroll
        for (int k = 0; k < 8; ++k) sum += __expf(vals[k] - rmax);
        #pragma unroll
        for (int off = 32; off >= 1; off >>= 1)
            sum += __shfl_xor(sum, off, 64);
        const float factor = dc[h] / sum;

        const int ddx = lane & 15, mgv = lane >> 4;
        const float* __restrict__ vb = Vw + ((size_t)(b * HH + h) * NN) * DKK;
        float av = 0.f;
        #pragma unroll 4
        for (int m = mgv; m < NN; m += 4) {
            const float p = __expf(ET[h * ETS2 + m] - rmax);
            av += p * vb[m * DKK + ddx];
        }
        av += __shfl_xor(av, 16, 64);
        av += __shfl_xor(av, 32, 64);
        if (mgv == 0) vout[h * DKK + ddx] = av * factor;
    }
    __syncthreads();

    if (t < DD) {
        float a3 = 0.f;
        #pragma unroll 4
        for (int d = 0; d < DD; ++d) a3 += vout[d] * O_n[d * DD + t];
        n_out[(size_t)bn * DD + t] = a3;
    }
}

extern "C" void kernel_launch(void* const* d_in, const int* in_sizes, int n_in,
                              void* d_out, int out_size, void* d_ws, size_t ws_size,
                              hipStream_t stream)
{
    const float* n_ptr = (const float*)d_in[0];
    const float* e     = (const float*)d_in[1];
    const float* W_qkv = (const float*)d_in[2];
    const float* O_n   = (const float*)d_in[3];
    const float* W_g   = (const float*)d_in[4];
    const float* W_e   = (const float*)d_in[5];
    const float* O_e   = (const float*)d_in[6];

    float* n_out = (float*)d_out;
    float* e_out = n_out + (size_t)BB * NN * DD;

    float* Qw    = (float*)d_ws;                          // 3 x 0.5MB
    float* Kw    = Qw + (size_t)BB * HH * NN * DKK;
    float* Vw    = Kw + (size_t)BB * HH * NN * DKK;
    float* QKc   = Vw + (size_t)BB * HH * NN * DKK;       // 16.8MB
    float* EH    = QKc + (size_t)BB * HH * NN * NN;       // 16.8MB
    float* Gpart = EH + (size_t)BB * NN * NN * HH;        // 64KB
    float* WegT  = Gpart + (size_t)BB * NN * 2 * HH;      // 8KB

    qkv_kernel<<<BB * NN + 16, 128, 0, stream>>>(n_ptr, W_qkv, W_g, W_e,
                                                 Qw, Kw, Vw, WegT);
    qk_kernel<<<BB * HH * 16, 256, 0, stream>>>(Qw, Kw, QKc);
    eg_kernel<<<BB * NN * 2, 256, 0, stream>>>(e, WegT, O_e, QKc,
                                               EH, Gpart, e_out);
    attn_kernel<<<BB * NN, 256, 0, stream>>>(EH, Gpart, Vw, O_n, n_out);
}

// Round 15
// 189.688 us; speedup vs baseline: 1.0032x; 1.0032x over previous
//
#include <hip/hip_runtime.h>
#include <math.h>

#define BB 2
#define NN 512
#define DD 128
#define HH 8
#define DKK 16
#define TR 64            // tile rows
#define NT 4             // tiles per block (256 rows)
#define ETS2 520         // attn LDS row stride

typedef __attribute__((ext_vector_type(8))) short short8;
typedef __attribute__((ext_vector_type(4))) float f32x4;

__device__ __forceinline__ float dot4(float4 a, float4 b) {
    return a.x*b.x + a.y*b.y + a.z*b.z + a.w*b.w;
}
// RNE f32 -> bf16 pack (a in low, b in high)
__device__ __forceinline__ unsigned pk_bf16(float a, float b) {
    unsigned ua = __float_as_uint(a), ub = __float_as_uint(b);
    ua = (ua + 0x7FFFu + ((ua >> 16) & 1u)) >> 16;
    ub = (ub + 0x7FFFu + ((ub >> 16) & 1u)) >> 16;
    return ua | (ub << 16);
}

// ---------------- Kernel 1: QKV projection + W_egT staging ----------------
__global__ __launch_bounds__(128)
void qkv_kernel(const float* __restrict__ n_in,
                const float* __restrict__ W_qkv,
                const float* __restrict__ W_g,
                const float* __restrict__ W_e,
                float* __restrict__ Qw, float* __restrict__ Kw,
                float* __restrict__ Vw, float* __restrict__ WegT)
{
    const int bid = blockIdx.x;
    if (bid >= BB * NN) {                    // 16 trailing blocks: WegT[col][d]
        const int col = bid - BB * NN;
        const int t = threadIdx.x;
        WegT[col * DD + t] = (col < 8) ? W_e[t * HH + col]
                                       : W_g[t * HH + (col - 8)];
        return;
    }
    __shared__ float nrow[DD];
    const int bn = bid;
    const int b  = bn >> 9;
    const int nr = bn & 511;
    const int t  = threadIdx.x;
    nrow[t] = n_in[(size_t)bn * DD + t];
    __syncthreads();
    const int h = t >> 4, dk = t & 15;
    const size_t dst = ((size_t)(b * HH + h) * NN + nr) * DKK + dk;
    float accq = 0.f, acck = 0.f, accv = 0.f;
    #pragma unroll 8
    for (int d = 0; d < DD; ++d) {
        const float nv = nrow[d];
        const float* wr = W_qkv + (size_t)d * 3 * DD;
        accq += nv * wr[t];
        acck += nv * wr[t + 128];
        accv += nv * wr[t + 256];
    }
    Qw[dst] = accq;
    Kw[dst] = acck;
    Vw[dst] = accv;
}

// ---------------- Kernel 1b: QKc = clamp(Q K^T * scale), [bn][h][m] ----------------
__global__ __launch_bounds__(256)
void qk_kernel(const float* __restrict__ Qw,
               const float* __restrict__ Kw,
               float* __restrict__ QKc)
{
    __shared__ __align__(16) float4 Kl[NN * 4];   // 32KB  [m][4]
    __shared__ __align__(16) float4 Ql[32 * 4];   // 2KB

    const int bid = blockIdx.x;
    const int qt  = bid & 15;
    const int h   = (bid >> 4) & 7;
    const int b   = bid >> 7;
    const int t   = threadIdx.x;

    const float4* __restrict__ kb =
        (const float4*)Kw + ((size_t)(b * HH + h) * NN) * 4;
    #pragma unroll
    for (int j = 0; j < 8; ++j) Kl[j * 256 + t] = kb[j * 256 + t];
    if (t < 128)
        Ql[t] = ((const float4*)Qw)[((size_t)(b * HH + h) * NN + qt * 32) * 4 + t];
    __syncthreads();

    const int qr = t >> 3;
    const int mq = t & 7;
    const float4 q0 = Ql[qr * 4 + 0];
    const float4 q1 = Ql[qr * 4 + 1];
    const float4 q2 = Ql[qr * 4 + 2];
    const float4 q3 = Ql[qr * 4 + 3];

    float4* __restrict__ out4 =
        (float4*)QKc + (((size_t)(b * NN + qt * 32 + qr) * HH + h) * NN) / 4;

    #pragma unroll 1
    for (int cc = 0; cc < 16; ++cc) {
        float4 r;
        float* rp = (float*)&r;
        #pragma unroll
        for (int i = 0; i < 4; ++i) {
            const int m = mq * 64 + cc * 4 + i;
            float s = dot4(q0, Kl[m*4+0]) + dot4(q1, Kl[m*4+1])
                    + dot4(q2, Kl[m*4+2]) + dot4(q3, Kl[m*4+3]);
            s *= 0.25f;
            rp[i] = fminf(5.f, fmaxf(-5.f, s));
        }
        out4[mq * 16 + cc] = r;
    }
}

// ---------------- Kernel 2: E/G MFMA + QKc add + EH + e_out (streaming) ----
// grid = B*N*2 (bn x 2 m-chunks of 256 rows), 256 threads = 4 waves.
// SINGLE bf16 e-tile buffer (LDS ~18.5KB -> 7-8 blocks/CU); STAGE_WRITE
// placed after e_out so in-flight loads land under e_out's VALU+stores.
__global__ __launch_bounds__(256)
void eg_kernel(const float* __restrict__ e,
               const float* __restrict__ WegT,
               const float* __restrict__ O_e,
               const float* __restrict__ QKc,
               float* __restrict__ EH,      // [B*N][m][h] _E
               float* __restrict__ Gpart,   // [B*N*2][H]
               float* __restrict__ e_out)
{
    __shared__ __align__(16) uint4 ebuf4[TR * 16];     // 16KB bf16 tile (single)
    __shared__ __align__(16) float ET2[TR * 8];        // 2KB [m][h]
    __shared__ float Gred[32];

    const int t    = threadIdx.x;
    const int bid  = blockIdx.x;
    const int bn   = bid >> 1;
    const int mc   = bid & 1;
    const int R0   = mc * 256;
    const int wq   = t >> 6;
    const int lane = t & 63;
    const int c    = lane & 15;      // MFMA col (W col / head)
    const int mq   = lane >> 4;      // C/D row group; A/B k-group
    const int c4o  = t & 31;         // e_out float4 column
    const int mg   = t >> 5;         // e_out row base 0..7

    const float4* __restrict__ e4 =
        (const float4*)e + ((size_t)bn * NN + R0) * 32;
    const float4* __restrict__ WegT4 = (const float4*)WegT;

    // B fragments: W[col=c][k], 4 k-steps (16 VGPR)
    short8 wB[4];
    #pragma unroll
    for (int kb = 0; kb < 4; ++kb) {
        const float4 wa = WegT4[c * 32 + kb * 8 + mq * 2];
        const float4 wb = WegT4[c * 32 + kb * 8 + mq * 2 + 1];
        uint4 u;
        u.x = pk_bf16(wa.x, wa.y); u.y = pk_bf16(wa.z, wa.w);
        u.z = pk_bf16(wb.x, wb.y); u.w = pk_bf16(wb.z, wb.w);
        wB[kb] = *(short8*)&u;
    }
    // O_e column cache (32 VGPR)
    float4 oe[8];
    #pragma unroll
    for (int h = 0; h < 8; ++h)
        oe[h] = ((const float4*)O_e)[h * 32 + c4o];

    // stage regs: 8 float4 (32 VGPR)
    float4 pa0, pb0, pa1, pb1, pa2, pb2, pa3, pb3;

    #define STAGE_LOAD(tile)                                                  \
    {                                                                         \
        const float4* __restrict__ sp = e4 + (size_t)(tile) * 2048 + 2 * t;   \
        pa0 = sp[0];    pb0 = sp[1];                                          \
        pa1 = sp[512];  pb1 = sp[513];                                        \
        pa2 = sp[1024]; pb2 = sp[1025];                                       \
        pa3 = sp[1536]; pb3 = sp[1537];                                       \
    }
    #define STAGE_W1(U, A, Bv)                                                \
    {                                                                         \
        const int u_ = (U), ms = u_ >> 4, ck = u_ & 15;                       \
        uint4 x;                                                              \
        x.x = pk_bf16(A.x, A.y);  x.y = pk_bf16(A.z, A.w);                    \
        x.z = pk_bf16(Bv.x, Bv.y); x.w = pk_bf16(Bv.z, Bv.w);                 \
        ebuf4[ms * 16 + (ck ^ (ms & 15))] = x;                                \
    }
    #define STAGE_WRITE()                                                     \
    {                                                                         \
        STAGE_W1(t,       pa0, pb0); STAGE_W1(t + 256, pa1, pb1);             \
        STAGE_W1(t + 512, pa2, pb2); STAGE_W1(t + 768, pa3, pb3);             \
    }

    float ga0 = 0.f, ga1 = 0.f, ga2 = 0.f, ga3 = 0.f;

    STAGE_LOAD(0);
    STAGE_WRITE();
    asm volatile("s_waitcnt lgkmcnt(0)" ::: "memory");
    __builtin_amdgcn_s_barrier();

    #pragma unroll
    for (int tt = 0; tt < NT; ++tt) {
        // QKc for this lane's 4 rows (issued early; latency hides under MFMA)
        float4 qk4 = {0.f, 0.f, 0.f, 0.f};
        if (c < 8)
            qk4 = *(const float4*)(QKc + ((size_t)bn * HH + c) * NN
                                   + R0 + tt * TR + wq * 16 + mq * 4);
        // issue next-tile loads NOW; consumed after e_out (long gap)
        if (tt + 1 < NT) STAGE_LOAD(tt + 1);

        // ---- MFMA ----
        const int mrow = wq * 16 + c;
        f32x4 acc = {0.f, 0.f, 0.f, 0.f};
        #pragma unroll
        for (int kb = 0; kb < 4; ++kb) {
            const int ck = kb * 4 + mq;
            uint4 av = ebuf4[mrow * 16 + (ck ^ (mrow & 15))];
            acc = __builtin_amdgcn_mfma_f32_16x16x32_bf16(
                      *(short8*)&av, wB[kb], acc, 0, 0, 0);
        }

        // ---- epilogue: _E -> ET2 + EH ; G accumulate ----
        const int mloc = wq * 16 + mq * 4;
        if (c < 8) {
            const float v0 = acc[0] + qk4.x;
            const float v1 = acc[1] + qk4.y;
            const float v2 = acc[2] + qk4.z;
            const float v3 = acc[3] + qk4.w;
            ET2[(mloc + 0) * 8 + c] = v0;
            ET2[(mloc + 1) * 8 + c] = v1;
            ET2[(mloc + 2) * 8 + c] = v2;
            ET2[(mloc + 3) * 8 + c] = v3;
            float* ehp = EH + ((size_t)bn * NN + R0 + tt * TR + mloc) * HH + c;
            ehp[0]  = v0;
            ehp[8]  = v1;
            ehp[16] = v2;
            ehp[24] = v3;
        } else {
            ga0 += 1.f / (1.f + __expf(-acc[0]));
            ga1 += 1.f / (1.f + __expf(-acc[1]));
            ga2 += 1.f / (1.f + __expf(-acc[2]));
            ga3 += 1.f / (1.f + __expf(-acc[3]));
        }
        asm volatile("s_waitcnt lgkmcnt(0)" ::: "memory");
        __builtin_amdgcn_s_barrier();        // ET2 ready; ebuf reads all done

        // ---- e_out tile (hides the in-flight next-tile loads) ----
        float4* __restrict__ out4 =
            (float4*)e_out + ((size_t)bn * NN + R0 + tt * TR) * 32;
        #pragma unroll
        for (int k = 0; k < 8; ++k) {
            const int m = mg + 8 * k;
            const float4 elo = *(const float4*)&ET2[m * 8];
            const float4 ehi = *(const float4*)&ET2[m * 8 + 4];
            float4 rr;
            rr.x = elo.x*oe[0].x + elo.y*oe[1].x + elo.z*oe[2].x + elo.w*oe[3].x
                 + ehi.x*oe[4].x + ehi.y*oe[5].x + ehi.z*oe[6].x + ehi.w*oe[7].x;
            rr.y = elo.x*oe[0].y + elo.y*oe[1].y + elo.z*oe[2].y + elo.w*oe[3].y
                 + ehi.x*oe[4].y + ehi.y*oe[5].y + ehi.z*oe[6].y + ehi.w*oe[7].y;
            rr.z = elo.x*oe[0].z + elo.y*oe[1].z + elo.z*oe[2].z + elo.w*oe[3].z
                 + ehi.x*oe[4].z + ehi.y*oe[5].z + ehi.z*oe[6].z + ehi.w*oe[7].z;
            rr.w = elo.x*oe[0].w + elo.y*oe[1].w + elo.z*oe[2].w + elo.w*oe[3].w
                 + ehi.x*oe[4].w + ehi.y*oe[5].w + ehi.z*oe[6].w + ehi.w*oe[7].w;
            out4[m * 32 + c4o] = rr;
        }

        // ---- refill the single buffer (loads have landed by now) ----
        if (tt + 1 < NT) {
            STAGE_WRITE();
            asm volatile("s_waitcnt lgkmcnt(0)" ::: "memory");
            __builtin_amdgcn_s_barrier();    // ebuf ready; e_out reads done
        }
    }

    // ---- G partial reduction -> Gpart[bid][h] ----
    if (c >= 8) {
        float s = ga0 + ga1 + ga2 + ga3;
        s += __shfl_xor(s, 16, 64);
        s += __shfl_xor(s, 32, 64);
        if (mq == 0) Gred[wq * 8 + (c - 8)] = s;
    }
    __syncthreads();
    if (t < 8) {
        Gpart[(size_t)bid * HH + t] =
            Gred[t] + Gred[8 + t] + Gred[16 + t] + Gred[24 + t];
    }
    #undef STAGE_LOAD
    #undef STAGE_W1
    #undef STAGE_WRITE
}

// ---------------- Kernel 3: softmax + AV + n_out ----------------
__global__ __launch_bounds__(256)
void attn_kernel(const float* __restrict__ EH,
                 const float* __restrict__ Gpart,
                 const float* __restrict__ Vw,
                 const float* __restrict__ O_n,
                 float* __restrict__ n_out)
{
    __shared__ float ET[HH * ETS2];   // 16.6KB [h][m], stride 520
    __shared__ float dc[HH];
    __shared__ __align__(16) float vout[DD];

    const int t    = threadIdx.x;
    const int bn   = blockIdx.x;
    const int b    = bn >> 9;
    const int wq   = t >> 6;
    const int lane = t & 63;

    // stage EH [m][h] -> ET [h][m] (coalesced float4 reads)
    const float4* __restrict__ eh4 = (const float4*)(EH + (size_t)bn * NN * HH);
    #pragma unroll
    for (int k = 0; k < 4; ++k) {
        const float4 f = eh4[t + 256 * k];
        const int idx = (t + 256 * k) << 2;
        const int m = idx >> 3, h0 = idx & 7;
        ET[(h0 + 0) * ETS2 + m] = f.x;
        ET[(h0 + 1) * ETS2 + m] = f.y;
        ET[(h0 + 2) * ETS2 + m] = f.z;
        ET[(h0 + 3) * ETS2 + m] = f.w;
    }
    if (t < HH)
        dc[t] = log1pf(Gpart[(size_t)bn * 2 * HH + t] +
                       Gpart[(size_t)bn * 2 * HH + HH + t]);
    __syncthreads();

    #pragma unroll 1
    for (int hw = 0; hw < 2; ++hw) {
        const int h = wq * 2 + hw;
        float vals[8];
        float rmax = -1e30f;
        #pragma unroll
        for (int k = 0; k < 8; ++k) {
            vals[k] = ET[h * ETS2 + k * 64 + lane];
            rmax = fmaxf(rmax, vals[k]);
        }
        #pragma unroll
        for (int off = 32; off >= 1; off >>= 1)
            rmax = fmaxf(rmax, __shfl_xor(rmax, off, 64));
        float sum = 0.f;
        #pragma unroll
        for (int k = 0; k < 8; ++k) sum += __expf(vals[k] - rmax);
        #pragma unroll
        for (int off = 32; off >= 1; off >>= 1)
            sum += __shfl_xor(sum, off, 64);
        const float factor = dc[h] / sum;

        const int ddx = lane & 15, mgv = lane >> 4;
        const float* __restrict__ vb = Vw + ((size_t)(b * HH + h) * NN) * DKK;
        float av = 0.f;
        #pragma unroll 4
        for (int m = mgv; m < NN; m += 4) {
            const float p = __expf(ET[h * ETS2 + m] - rmax);
            av += p * vb[m * DKK + ddx];
        }
        av += __shfl_xor(av, 16, 64);
        av += __shfl_xor(av, 32, 64);
        if (mgv == 0) vout[h * DKK + ddx] = av * factor;
    }
    __syncthreads();

    if (t < DD) {
        float a3 = 0.f;
        #pragma unroll 4
        for (int d = 0; d < DD; ++d) a3 += vout[d] * O_n[d * DD + t];
        n_out[(size_t)bn * DD + t] = a3;
    }
}

extern "C" void kernel_launch(void* const* d_in, const int* in_sizes, int n_in,
                              void* d_out, int out_size, void* d_ws, size_t ws_size,
                              hipStream_t stream)
{
    const float* n_ptr = (const float*)d_in[0];
    const float* e     = (const float*)d_in[1];
    const float* W_qkv = (const float*)d_in[2];
    const float* O_n   = (const float*)d_in[3];
    const float* W_g   = (const float*)d_in[4];
    const float* W_e   = (const float*)d_in[5];
    const float* O_e   = (const float*)d_in[6];

    float* n_out = (float*)d_out;
    float* e_out = n_out + (size_t)BB * NN * DD;

    float* Qw    = (float*)d_ws;                          // 3 x 0.5MB
    float* Kw    = Qw + (size_t)BB * HH * NN * DKK;
    float* Vw    = Kw + (size_t)BB * HH * NN * DKK;
    float* QKc   = Vw + (size_t)BB * HH * NN * DKK;       // 16.8MB
    float* EH    = QKc + (size_t)BB * HH * NN * NN;       // 16.8MB
    float* Gpart = EH + (size_t)BB * NN * NN * HH;        // 64KB
    float* WegT  = Gpart + (size_t)BB * NN * 2 * HH;      // 8KB

    qkv_kernel<<<BB * NN + 16, 128, 0, stream>>>(n_ptr, W_qkv, W_g, W_e,
                                                 Qw, Kw, Vw, WegT);
    qk_kernel<<<BB * HH * 16, 256, 0, stream>>>(Qw, Kw, QKc);
    eg_kernel<<<BB * NN * 2, 256, 0, stream>>>(e, WegT, O_e, QKc,
                                               EH, Gpart, e_out);
    attn_kernel<<<BB * NN, 256, 0, stream>>>(EH, Gpart, Vw, O_n, n_out);
}

// Round 16
// 172.530 us; speedup vs baseline: 1.1029x; 1.0994x over previous
//
#include <hip/hip_runtime.h>
#include <math.h>

#define BB 2
#define NN 512
#define DD 128
#define HH 8
#define DKK 16
#define TR 128           // tile rows
#define NT (NN / TR)     // 4 tiles per (b,n)
#define ETS 516          // padded ET row stride (516 % 32 = 4 -> conflict-free RMW)

typedef __attribute__((ext_vector_type(8))) short short8;
typedef __attribute__((ext_vector_type(4))) float f32x4;

__device__ __forceinline__ float dot4(float4 a, float4 b) {
    return a.x*b.x + a.y*b.y + a.z*b.z + a.w*b.w;
}
// RNE f32 -> bf16 pack (a in low, b in high)
__device__ __forceinline__ unsigned pk_bf16(float a, float b) {
    unsigned ua = __float_as_uint(a), ub = __float_as_uint(b);
    ua = (ua + 0x7FFFu + ((ua >> 16) & 1u)) >> 16;
    ub = (ub + 0x7FFFu + ((ub >> 16) & 1u)) >> 16;
    return ua | (ub << 16);
}

// ---------------- Kernel 1: QKV projection + W_egT staging ----------------
__global__ __launch_bounds__(128)
void qkv_kernel(const float* __restrict__ n_in,
                const float* __restrict__ W_qkv,
                const float* __restrict__ W_g,
                const float* __restrict__ W_e,
                float* __restrict__ Qw, float* __restrict__ Kw,
                float* __restrict__ Vw, float* __restrict__ WegT)
{
    const int bid = blockIdx.x;
    if (bid >= BB * NN) {                    // 16 trailing blocks: WegT[col][d]
        const int col = bid - BB * NN;
        const int t = threadIdx.x;
        WegT[col * DD + t] = (col < 8) ? W_e[t * HH + col]
                                       : W_g[t * HH + (col - 8)];
        return;
    }
    __shared__ float nrow[DD];
    const int bn = bid;
    const int b  = bn >> 9;
    const int nr = bn & 511;
    const int t  = threadIdx.x;
    nrow[t] = n_in[(size_t)bn * DD + t];
    __syncthreads();
    const int h = t >> 4, dk = t & 15;
    const size_t dst = ((size_t)(b * HH + h) * NN + nr) * DKK + dk;
    float accq = 0.f, acck = 0.f, accv = 0.f;
    #pragma unroll 8
    for (int d = 0; d < DD; ++d) {
        const float nv = nrow[d];
        const float* wr = W_qkv + (size_t)d * 3 * DD;
        accq += nv * wr[t];
        acck += nv * wr[t + 128];
        accv += nv * wr[t + 256];
    }
    Qw[dst] = accq;
    Kw[dst] = acck;
    Vw[dst] = accv;
}

// ---------------- Kernel 2: fully fused QK + E/G (MFMA) + per-tile e_out +
// softmax/AV + n_out. One block per (b,n), 512 threads = 8 waves.
// Per tile: stage-load(t+1) -> MFMA -> ET RMW -> barrier -> e_out tile
// (write stream overlaps in-flight reads) -> STAGE_WRITE -> barrier.
__global__ __attribute__((amdgpu_flat_work_group_size(512, 512),
                          amdgpu_waves_per_eu(2, 4)))
void eg_kernel(const float* __restrict__ e,
               const float* __restrict__ WegT,
               const float* __restrict__ O_e,
               const float* __restrict__ Qw,
               const float* __restrict__ Kw,
               const float* __restrict__ Vw,
               const float* __restrict__ O_n,
               float* __restrict__ n_out,
               float* __restrict__ e_out)
{
    __shared__ __align__(16) uint4 ebuf4[TR * 16];   // 32KB bf16 tile (single)
    __shared__ __align__(16) float ET[HH * ETS];     // 16.5KB persistent _E [h][m]
    __shared__ float Gred[64];
    __shared__ float dc[HH];
    __shared__ __align__(16) float vout[DD];

    const int t    = threadIdx.x;
    const int bn   = blockIdx.x;
    const int b    = bn >> 9;
    const int nr   = bn & 511;
    const int wq   = t >> 6;
    const int lane = t & 63;
    const int c    = lane & 15;      // MFMA C/D col (= W col / head)
    const int mq   = lane >> 4;      // C/D row group; also A/B k-group
    const int c4o  = t & 31;         // e_out float4 column
    const int mr0  = t >> 5;         // e_out row base 0..15

    const float4* __restrict__ e4    = (const float4*)e + (size_t)bn * NN * 32;
    const float4* __restrict__ WegT4 = (const float4*)WegT;

    // ---- B fragments: W[col=c][k] -> bf16, 4 k-steps (16 VGPR) ----
    short8 wB[4];
    #pragma unroll
    for (int kb = 0; kb < 4; ++kb) {
        const float4 wa = WegT4[c * 32 + kb * 8 + mq * 2];
        const float4 wb = WegT4[c * 32 + kb * 8 + mq * 2 + 1];
        uint4 u;
        u.x = pk_bf16(wa.x, wa.y); u.y = pk_bf16(wa.z, wa.w);
        u.z = pk_bf16(wb.x, wb.y); u.w = pk_bf16(wb.z, wb.w);
        wB[kb] = *(short8*)&u;
    }
    // ---- O_e column cache (32 VGPR) ----
    float4 oe[8];
    #pragma unroll
    for (int h = 0; h < 8; ++h)
        oe[h] = ((const float4*)O_e)[h * 32 + c4o];

    // stage-load regs: 8 float4 (32 VGPR)
    float4 pa0, pa1, pa2, pa3, pb0, pb1, pb2, pb3;

    #define STAGE_LOAD(tile)                                                  \
    {                                                                         \
        const float4* __restrict__ sp = e4 + (size_t)(tile) * 4096 + 2 * t;   \
        pa0 = sp[0];    pb0 = sp[1];                                          \
        pa1 = sp[1024]; pb1 = sp[1025];                                       \
        pa2 = sp[2048]; pb2 = sp[2049];                                       \
        pa3 = sp[3072]; pb3 = sp[3073];                                       \
    }
    #define STAGE_WRITE(P, A, B)                                              \
    {                                                                         \
        const int ms = (P) * 32 + (t >> 4), ck = t & 15;                      \
        uint4 u;                                                              \
        u.x = pk_bf16(A.x, A.y); u.y = pk_bf16(A.z, A.w);                     \
        u.z = pk_bf16(B.x, B.y); u.w = pk_bf16(B.z, B.w);                     \
        ebuf4[ms * 16 + (ck ^ (ms & 15))] = u;                                \
    }
    #define STAGE_WRITE_ALL()                                                 \
    {                                                                         \
        STAGE_WRITE(0, pa0, pb0); STAGE_WRITE(1, pa1, pb1);                   \
        STAGE_WRITE(2, pa2, pb2); STAGE_WRITE(3, pa3, pb3);                   \
    }

    float ga0 = 0.f, ga1 = 0.f, ga2 = 0.f, ga3 = 0.f;

    // ---- prologue: issue tile-0 e loads (HBM), then QK scores (L2) ----
    STAGE_LOAD(0);

    {   // wave wq = head h; clamped scores -> ET[h][m]
        const int h = wq;
        const float4* __restrict__ qp =
            (const float4*)(Qw + ((size_t)(b * HH + h) * NN + nr) * DKK);
        const float4 q0 = qp[0], q1 = qp[1], q2 = qp[2], q3 = qp[3];
        const float4* __restrict__ kb =
            (const float4*)(Kw + ((size_t)(b * HH + h) * NN) * DKK);
        #pragma unroll
        for (int k = 0; k < 8; ++k) {
            const int m = k * 64 + lane;
            float s = dot4(q0, kb[m * 4 + 0]) + dot4(q1, kb[m * 4 + 1])
                    + dot4(q2, kb[m * 4 + 2]) + dot4(q3, kb[m * 4 + 3]);
            s *= 0.25f;
            ET[h * ETS + m] = fminf(5.f, fmaxf(-5.f, s));
        }
    }

    STAGE_WRITE_ALL();
    asm volatile("s_waitcnt lgkmcnt(0)" ::: "memory");
    __builtin_amdgcn_s_barrier();

    #pragma unroll
    for (int tt = 0; tt < NT; ++tt) {
        // prefetch next tile into regs (consumed after e_out -> long gap)
        if (tt + 1 < NT) STAGE_LOAD(tt + 1);

        // ---- MFMA: E/G for this wave's 16 rows x 16 cols ----
        const int mrow = wq * 16 + c;
        f32x4 acc = {0.f, 0.f, 0.f, 0.f};
        #pragma unroll
        for (int kb = 0; kb < 4; ++kb) {
            const int ck = kb * 4 + mq;
            uint4 av = ebuf4[mrow * 16 + (ck ^ (mrow & 15))];
            acc = __builtin_amdgcn_mfma_f32_16x16x32_bf16(
                      *(short8*)&av, wB[kb], acc, 0, 0, 0);
        }

        // ---- epilogue: _E = acc + clamped_score (LDS RMW) / G accumulate ----
        const int mloc = tt * TR + wq * 16 + mq * 4;
        if (c < 8) {
            float4 prev = *(float4*)&ET[c * ETS + mloc];
            prev.x += acc[0]; prev.y += acc[1];
            prev.z += acc[2]; prev.w += acc[3];
            *(float4*)&ET[c * ETS + mloc] = prev;
        } else {
            ga0 += 1.f / (1.f + __expf(-acc[0]));
            ga1 += 1.f / (1.f + __expf(-acc[1]));
            ga2 += 1.f / (1.f + __expf(-acc[2]));
            ga3 += 1.f / (1.f + __expf(-acc[3]));
        }
        asm volatile("s_waitcnt lgkmcnt(0)" ::: "memory");
        __builtin_amdgcn_s_barrier();   // ET tile final; ebuf reads done

        // ---- e_out tile (write stream; hides in-flight next-tile reads) ----
        {
            float4* __restrict__ out4 =
                (float4*)e_out + ((size_t)bn * NN + tt * TR) * 32;
            #pragma unroll
            for (int it = 0; it < 8; ++it) {
                const int m = tt * TR + mr0 + it * 16;
                float4 rr{0.f, 0.f, 0.f, 0.f};
                #pragma unroll
                for (int h = 0; h < 8; ++h) {
                    const float ev = ET[h * ETS + m];   // broadcast read
                    rr.x += ev * oe[h].x;
                    rr.y += ev * oe[h].y;
                    rr.z += ev * oe[h].z;
                    rr.w += ev * oe[h].w;
                }
                out4[(mr0 + it * 16) * 32 + c4o] = rr;
            }
        }

        // ---- refill ebuf from prefetched regs (loads landed under e_out) ----
        if (tt + 1 < NT) {
            STAGE_WRITE_ALL();
            asm volatile("s_waitcnt lgkmcnt(0)" ::: "memory");
            __builtin_amdgcn_s_barrier();
        }
    }

    // ---- G reduction -> dyn_cent ----
    if (c >= 8) {
        float s = ga0 + ga1 + ga2 + ga3;
        s += __shfl_xor(s, 16, 64);
        s += __shfl_xor(s, 32, 64);
        if (lane < 16) Gred[wq * 8 + (c - 8)] = s;
    }
    __syncthreads();
    if (t < 8) {
        float s = 0.f;
        #pragma unroll
        for (int w = 0; w < 8; ++w) s += Gred[w * 8 + t];
        dc[t] = log1pf(s);
    }
    __syncthreads();

    // ---- softmax + AV: wave wq owns head wq ----
    {
        const int h = wq;
        float vals[8];
        float rmax = -1e30f;
        #pragma unroll
        for (int k = 0; k < 8; ++k) {
            vals[k] = ET[h * ETS + k * 64 + lane];
            rmax = fmaxf(rmax, vals[k]);
        }
        #pragma unroll
        for (int off = 32; off >= 1; off >>= 1)
            rmax = fmaxf(rmax, __shfl_xor(rmax, off, 64));
        float sum = 0.f;
        #pragma unroll
        for (int k = 0; k < 8; ++k) sum += __expf(vals[k] - rmax);
        #pragma unroll
        for (int off = 32; off >= 1; off >>= 1)
            sum += __shfl_xor(sum, off, 64);
        const float factor = dc[h] / sum;

        const int ddx = lane & 15, mg = lane >> 4;
        const float* __restrict__ vb = Vw + ((size_t)(b * HH + h) * NN) * DKK;
        float av = 0.f;
        #pragma unroll 4
        for (int m = mg; m < NN; m += 4) {
            const float p = __expf(ET[h * ETS + m] - rmax);
            av += p * vb[m * DKK + ddx];
        }
        av += __shfl_xor(av, 16, 64);
        av += __shfl_xor(av, 32, 64);
        if (mg == 0) vout[h * DKK + ddx] = av * factor;
    }
    __syncthreads();

    // ---- n_out = vout @ O_n ----
    if (t < DD) {
        float a3 = 0.f;
        #pragma unroll 4
        for (int d = 0; d < DD; ++d) a3 += vout[d] * O_n[d * DD + t];
        n_out[(size_t)bn * DD + t] = a3;
    }
    #undef STAGE_LOAD
    #undef STAGE_WRITE
    #undef STAGE_WRITE_ALL
}

extern "C" void kernel_launch(void* const* d_in, const int* in_sizes, int n_in,
                              void* d_out, int out_size, void* d_ws, size_t ws_size,
                              hipStream_t stream)
{
    const float* n_ptr = (const float*)d_in[0];
    const float* e     = (const float*)d_in[1];
    const float* W_qkv = (const float*)d_in[2];
    const float* O_n   = (const float*)d_in[3];
    const float* W_g   = (const float*)d_in[4];
    const float* W_e   = (const float*)d_in[5];
    const float* O_e   = (const float*)d_in[6];

    float* n_out = (float*)d_out;
    float* e_out = n_out + (size_t)BB * NN * DD;

    float* Qw   = (float*)d_ws;                          // 3 x 0.5MB
    float* Kw   = Qw + (size_t)BB * HH * NN * DKK;
    float* Vw   = Kw + (size_t)BB * HH * NN * DKK;
    float* WegT = Vw + (size_t)BB * HH * NN * DKK;       // 8KB

    qkv_kernel<<<BB * NN + 16, 128, 0, stream>>>(n_ptr, W_qkv, W_g, W_e,
                                                 Qw, Kw, Vw, WegT);
    eg_kernel<<<BB * NN, 512, 0, stream>>>(e, WegT, O_e, Qw, Kw, Vw, O_n,
                                           n_out, e_out);
}